// Round 17
// baseline (346.364 us; speedup 1.0000x reference)
//
#include <hip/hip_runtime.h>

#define N_NODES 100000
#define N_EDGES 1600000
#define B_GRAPHS 64
#define BN_EPS 1e-5
#define NBMAX 3200    // max per-layer stats-partial blocks (L3 uses 3125)

#define NBUCK 256
#define BUCK_NODES 392   // 256*392 = 100352 >= N_NODES; 392 < 512 -> 9-bit local id
#define PART_CHUNK 4096
#define NB_PART 391      // cdiv(N_EDGES, PART_CHUNK)
#define EMAX_LDS 8192    // LDS edge-staging cap (bucket avg 6272, sigma ~79 -> +24 sigma)

typedef _Float16 half4_t __attribute__((ext_vector_type(4)));

static inline int cdiv(long long a, int b) { return (int)((a + b - 1) / b); }

// ---------------- phase 1: bucket histogram of col ----------------
__global__ void part_hist_kernel(const int* __restrict__ col, int* __restrict__ bucket_cnt) {
    __shared__ int h[NBUCK];
    for (int i = threadIdx.x; i < NBUCK; i += 256) h[i] = 0;
    __syncthreads();
    long long ebase = (long long)blockIdx.x * PART_CHUNK;
    int n = (N_EDGES - ebase < PART_CHUNK) ? (int)(N_EDGES - ebase) : PART_CHUNK;
    for (int i = threadIdx.x; i < n; i += 256)
        atomicAdd(&h[col[ebase + i] / BUCK_NODES], 1);
    __syncthreads();
    for (int i = threadIdx.x; i < NBUCK; i += 256)
        if (h[i]) atomicAdd(&bucket_cnt[i], h[i]);
}

// ---------------- phase 2: scan bucket counts -> base & cursor ----------------
__global__ void part_scan_kernel(const int* __restrict__ bucket_cnt, int* __restrict__ bucket_base,
                                 int* __restrict__ bucket_cur) {
    __shared__ int s[NBUCK];
    int t = threadIdx.x;
    int v = bucket_cnt[t];
    s[t] = v;
    __syncthreads();
    for (int off = 1; off < NBUCK; off <<= 1) {
        int u = (t >= off) ? s[t - off] : 0;
        __syncthreads();
        s[t] += u;
        __syncthreads();
    }
    bucket_base[t] = s[t] - v;  // exclusive
    bucket_cur[t] = s[t] - v;
}

// ---------------- phase 3: partition edges; pack (row,local_col) into one uint ----------------
// Order within bucket is nondeterministic; neutralized by the per-node sort in csr_build.
__global__ void part_scatter_kernel(const int* __restrict__ row, const int* __restrict__ col,
                                    int* __restrict__ bucket_cur, unsigned* __restrict__ part_edges) {
    __shared__ int h[NBUCK];
    __shared__ int base_s[NBUCK];
    __shared__ int cur_s[NBUCK];
    long long ebase = (long long)blockIdx.x * PART_CHUNK;
    int n = (N_EDGES - ebase < PART_CHUNK) ? (int)(N_EDGES - ebase) : PART_CHUNK;
    for (int i = threadIdx.x; i < NBUCK; i += 256) h[i] = 0;
    __syncthreads();
    for (int i = threadIdx.x; i < n; i += 256)
        atomicAdd(&h[col[ebase + i] / BUCK_NODES], 1);
    __syncthreads();
    for (int i = threadIdx.x; i < NBUCK; i += 256) {
        int c = h[i];
        base_s[i] = c ? atomicAdd(&bucket_cur[i], c) : 0;
        cur_s[i] = 0;
    }
    __syncthreads();
    for (int i = threadIdx.x; i < n; i += 256) {
        int r = row[ebase + i], c = col[ebase + i];
        int bkt = c / BUCK_NODES;
        int p = base_s[bkt] + atomicAdd(&cur_s[bkt], 1);
        part_edges[p] = ((unsigned)r << 9) | (unsigned)(c - bkt * BUCK_NODES);
    }
}

// ---------------- phase 4: per-bucket CSR build + PER-NODE SORT (determinism) + fused scale_x ----------------
// Sorting each node's adjacency by source id makes the gather summation order run-to-run
// deterministic (scatter atomics produce arbitrary order; duplicates are identical).
__global__ void csr_build_kernel(const int* __restrict__ bucket_base, const unsigned* __restrict__ part_edges,
                                 int* __restrict__ row_ptr, int* __restrict__ deg,
                                 float* __restrict__ dis, int* __restrict__ sorted_row,
                                 const float* __restrict__ x, _Float16* __restrict__ xs4) {
    __shared__ int hist[BUCK_NODES];  // histogram, then reused as scatter cursors
    __shared__ int tsum[256];
    __shared__ int eLDS[EMAX_LDS];    // LDS staging for the bucket's edges
    int b = blockIdx.x;
    int t = threadIdx.x;
    int nbase = b * BUCK_NODES;
    int ebase = bucket_base[b];
    int eend = (b == NBUCK - 1) ? N_EDGES : bucket_base[b + 1];
    int ne = eend - ebase;
    bool use_lds = (ne <= EMAX_LDS);
    for (int i = t; i < BUCK_NODES; i += 256) hist[i] = 0;
    __syncthreads();
    for (int i = t; i < ne; i += 256)
        atomicAdd(&hist[part_edges[ebase + i] & 511u], 1);
    __syncthreads();
    int a0 = 0, a1 = 0;
    if (t < BUCK_NODES / 2) { a0 = hist[2 * t]; a1 = hist[2 * t + 1]; tsum[t] = a0 + a1; }
    else tsum[t] = 0;
    __syncthreads();
    for (int off = 1; off < 256; off <<= 1) {
        int u = (t >= off) ? tsum[t - off] : 0;
        __syncthreads();
        tsum[t] += u;
        __syncthreads();
    }
    if (t < BUCK_NODES / 2) {
        int excl = tsum[t] - (a0 + a1);
        hist[2 * t] = excl;
        hist[2 * t + 1] = excl + a0;
        int n0 = nbase + 2 * t, n1 = n0 + 1;
        if (n0 < N_NODES) {
            row_ptr[n0] = ebase + excl;
            deg[n0] = a0;
            dis[n0] = rsqrtf((float)a0 + 1.0f);
        }
        if (n1 < N_NODES) {
            row_ptr[n1] = ebase + excl + a0;
            deg[n1] = a1;
            dis[n1] = rsqrtf((float)a1 + 1.0f);
        }
    }
    __syncthreads();
    // scatter into LDS (or global fallback)
    for (int i = t; i < ne; i += 256) {
        unsigned e = part_edges[ebase + i];
        int p = atomicAdd(&hist[e & 511u], 1);
        if (use_lds) eLDS[p] = (int)(e >> 9);
        else sorted_row[ebase + p] = (int)(e >> 9);
    }
    __syncthreads();
    // per-node insertion sort (deterministic multiset order)
    for (int i = t; i < BUCK_NODES; i += 256) {
        int n = nbase + i;
        if (n >= N_NODES) continue;
        int s = row_ptr[n] - ebase;
        int d = deg[n];
        if (use_lds) {
            for (int a = 1; a < d; a++) {
                int key = eLDS[s + a];
                int j = a - 1;
                while (j >= 0 && eLDS[s + j] > key) { eLDS[s + j + 1] = eLDS[s + j]; j--; }
                eLDS[s + j + 1] = key;
            }
        } else {
            int* seg = sorted_row + ebase + s;
            for (int a = 1; a < d; a++) {
                int key = seg[a];
                int j = a - 1;
                while (j >= 0 && seg[j] > key) { seg[j + 1] = seg[j]; j--; }
                seg[j + 1] = key;
            }
        }
    }
    if (use_lds) {
        __syncthreads();
        for (int i = t; i < ne; i += 256) sorted_row[ebase + i] = eLDS[i];  // coalesced
    }
    // fused scale_x for this bucket's nodes
    for (int i = t; i < BUCK_NODES; i += 256) {
        int n = nbase + i;
        if (n < N_NODES) {
            float d = dis[n];
            half4_t v;
            v.x = (_Float16)(x[n * 3 + 0] * d);
            v.y = (_Float16)(x[n * 3 + 1] * d);
            v.z = (_Float16)(x[n * 3 + 2] * d);
            v.w = (_Float16)0.f;
            ((half4_t*)xs4)[n] = v;
        }
    }
}

// ---------------- FUSED: CSR gather (f16x4 lanes, x8 unroll) -> LDS -> matmul -> fp16 pre + fp64 stats ----------------
template <int IN, int OUT, int INSTRIDE>
__global__ void gather_mm_kernel(const int* __restrict__ row_ptr, const int* __restrict__ deg,
                                 const int* __restrict__ sorted_row, const float* __restrict__ dis,
                                 const _Float16* __restrict__ hs, const float* __restrict__ W,
                                 const float* __restrict__ b, _Float16* __restrict__ pre,
                                 double* __restrict__ part_s, double* __restrict__ part_q) {
    const int LPN = INSTRIDE / 4;  // lanes per node
    const int NPW = 64 / LPN;      // nodes per wave
    const int NPB = 4 * NPW;       // nodes per block (256 threads)
    __shared__ float lds_agg[1024];  // NPB * INSTRIDE == 1024 floats always
    __shared__ float Ws[IN * OUT];
    __shared__ double s_s[256];
    __shared__ double s_q[256];
    int tid = threadIdx.x;
    for (int k = tid; k < IN * OUT; k += 256) Ws[k] = W[k];

    // ---- gather phase (x8 unrolled for MLP; mean degree 16)
    int wv = tid >> 6, lane = tid & 63;
    int jn = wv * NPW + lane / LPN;  // node index within block
    int p = lane % LPN;              // feature-quad index
    int n = blockIdx.x * NPB + jn;
    if (n < N_NODES) {
        int start = row_ptr[n];
        int d = deg[n];
        const int* sr = sorted_row + start;
        const half4_t* h4 = (const half4_t*)hs;
        half4_t v = h4[(long long)n * LPN + p];
        float acc0 = (float)v.x, acc1 = (float)v.y, acc2 = (float)v.z, acc3 = (float)v.w;
        int j = 0;
        for (; j + 8 <= d; j += 8) {
            int r0 = sr[j], r1 = sr[j + 1], r2 = sr[j + 2], r3 = sr[j + 3];
            int r4 = sr[j + 4], r5 = sr[j + 5], r6 = sr[j + 6], r7 = sr[j + 7];
            half4_t a0 = h4[(long long)r0 * LPN + p];
            half4_t a1 = h4[(long long)r1 * LPN + p];
            half4_t a2 = h4[(long long)r2 * LPN + p];
            half4_t a3 = h4[(long long)r3 * LPN + p];
            half4_t a4 = h4[(long long)r4 * LPN + p];
            half4_t a5 = h4[(long long)r5 * LPN + p];
            half4_t a6 = h4[(long long)r6 * LPN + p];
            half4_t a7 = h4[(long long)r7 * LPN + p];
            acc0 += (((float)a0.x + (float)a1.x) + ((float)a2.x + (float)a3.x)) +
                    (((float)a4.x + (float)a5.x) + ((float)a6.x + (float)a7.x));
            acc1 += (((float)a0.y + (float)a1.y) + ((float)a2.y + (float)a3.y)) +
                    (((float)a4.y + (float)a5.y) + ((float)a6.y + (float)a7.y));
            acc2 += (((float)a0.z + (float)a1.z) + ((float)a2.z + (float)a3.z)) +
                    (((float)a4.z + (float)a5.z) + ((float)a6.z + (float)a7.z));
            acc3 += (((float)a0.w + (float)a1.w) + ((float)a2.w + (float)a3.w)) +
                    (((float)a4.w + (float)a5.w) + ((float)a6.w + (float)a7.w));
        }
        for (; j + 4 <= d; j += 4) {
            int r0 = sr[j], r1 = sr[j + 1], r2 = sr[j + 2], r3 = sr[j + 3];
            half4_t a0 = h4[(long long)r0 * LPN + p];
            half4_t a1 = h4[(long long)r1 * LPN + p];
            half4_t a2 = h4[(long long)r2 * LPN + p];
            half4_t a3 = h4[(long long)r3 * LPN + p];
            acc0 += ((float)a0.x + (float)a1.x) + ((float)a2.x + (float)a3.x);
            acc1 += ((float)a0.y + (float)a1.y) + ((float)a2.y + (float)a3.y);
            acc2 += ((float)a0.z + (float)a1.z) + ((float)a2.z + (float)a3.z);
            acc3 += ((float)a0.w + (float)a1.w) + ((float)a2.w + (float)a3.w);
        }
        for (; j < d; j++) {
            half4_t a = h4[(long long)sr[j] * LPN + p];
            acc0 += (float)a.x;
            acc1 += (float)a.y;
            acc2 += (float)a.z;
            acc3 += (float)a.w;
        }
        float dn = dis[n];
        float* dst = &lds_agg[(jn * LPN + p) * 4];
        dst[0] = dn * acc0;
        dst[1] = dn * acc1;
        dst[2] = dn * acc2;
        dst[3] = dn * acc3;
    }
    __syncthreads();

    // ---- matmul + stats phase
    const int NG = 256 / OUT;  // node groups
    int o = tid % OUT;
    int g = tid / OUT;
    float bo = b[o];
    double my_s = 0.0, my_q = 0.0;
    for (int j = g; j < NPB; j += NG) {
        int nn = blockIdx.x * NPB + j;
        if (nn < N_NODES) {
            float acc = bo;
#pragma unroll
            for (int k = 0; k < IN; k++) acc += lds_agg[j * INSTRIDE + k] * Ws[k * OUT + o];
            _Float16 q = (_Float16)acc;
            pre[(long long)nn * OUT + o] = q;
            float fq = (float)q;  // stats on quantized values
            my_s += (double)fq;
            my_q += (double)fq * (double)fq;
        }
    }
    s_s[tid] = my_s;
    s_q[tid] = my_q;
    __syncthreads();
    if (tid < OUT) {
        double ts = 0.0, tq = 0.0;
        for (int k = tid; k < 256; k += OUT) { ts += s_s[k]; tq += s_q[k]; }
        part_s[(long long)tid * NBMAX + blockIdx.x] = ts;
        part_q[(long long)tid * NBMAX + blockIdx.x] = tq;
    }
}

// ---------------- finalize BN stats: one block per feature, variable #partials ----------------
__global__ void bn_finalize_kernel(const double* __restrict__ part_s, const double* __restrict__ part_q,
                                   int nb, float* __restrict__ bn_mean, float* __restrict__ bn_rstd) {
    __shared__ double s_s[256];
    __shared__ double s_q[256];
    int o = blockIdx.x;
    int t = threadIdx.x;
    double ms = 0.0, mq = 0.0;
    for (int k = t; k < nb; k += 256) {
        ms += part_s[(long long)o * NBMAX + k];
        mq += part_q[(long long)o * NBMAX + k];
    }
    s_s[t] = ms;
    s_q[t] = mq;
    __syncthreads();
    for (int off = 128; off > 0; off >>= 1) {
        if (t < off) { s_s[t] += s_s[t + off]; s_q[t] += s_q[t + off]; }
        __syncthreads();
    }
    if (t == 0) {
        double mean = s_s[0] / (double)N_NODES;
        double var = s_q[0] / (double)N_NODES - mean * mean;
        bn_mean[o] = (float)mean;
        bn_rstd[o] = (float)(1.0 / sqrt(var + BN_EPS));
    }
}

// ---------------- BN apply + ReLU, half4-vectorized; fp16 in, fp16 out ----------------
template <int F, bool SCALE>
__global__ void bn_relu_kernel(const _Float16* __restrict__ pre, const float* __restrict__ bn_mean,
                               const float* __restrict__ bn_rstd, const float* __restrict__ g,
                               const float* __restrict__ be, const float* __restrict__ dis,
                               _Float16* __restrict__ out) {
    const int GP = F / 4;  // half4 groups per node
    int t = blockIdx.x * blockDim.x + threadIdx.x;
    const int total = N_NODES * GP;
    if (t >= total) return;
    int gi = t % GP;
    int f0 = gi * 4;
    half4_t v = ((const half4_t*)pre)[t];
    float d = SCALE ? dis[t / GP] : 1.0f;
    half4_t o;
#pragma unroll
    for (int k = 0; k < 4; k++) {
        int f = f0 + k;
        float y = ((float)v[k] - bn_mean[f]) * bn_rstd[f] * g[f] + be[f];
        y = y > 0.f ? y : 0.f;
        if (SCALE) y *= d;
        o[k] = (_Float16)y;
    }
    ((half4_t*)out)[t] = o;
}

// ---------------- mean pool with FUSED BN3+ReLU (reads fp16 PRE directly) ----------------
#define POOL_CHUNK 32
__global__ void pool_kernel(const _Float16* __restrict__ pre, const int* __restrict__ batch,
                            const float* __restrict__ bn_mean, const float* __restrict__ bn_rstd,
                            const float* __restrict__ g, const float* __restrict__ be,
                            float* __restrict__ pooled, float* __restrict__ cnt) {
    int wave = (blockIdx.x * blockDim.x + threadIdx.x) >> 6;
    int lane = threadIdx.x & 63;  // feature index
    int start = wave * POOL_CHUNK;
    if (start >= N_NODES) return;
    int end = start + POOL_CHUNK;
    if (end > N_NODES) end = N_NODES;
    float A = bn_rstd[lane] * g[lane];
    float B = be[lane] - bn_mean[lane] * A;
    int cur = batch[start];  // wave-uniform -> scalar load
    float acc = 0.f;
    float c = 0.f;
    int i = start;
    for (; i + 4 <= end; i += 4) {
        int b0 = batch[i], b1 = batch[i + 1], b2 = batch[i + 2], b3 = batch[i + 3];
        float v0 = fmaxf(0.f, fmaf((float)pre[(long long)i * 64 + lane], A, B));
        float v1 = fmaxf(0.f, fmaf((float)pre[(long long)(i + 1) * 64 + lane], A, B));
        float v2 = fmaxf(0.f, fmaf((float)pre[(long long)(i + 2) * 64 + lane], A, B));
        float v3 = fmaxf(0.f, fmaf((float)pre[(long long)(i + 3) * 64 + lane], A, B));
        if (b0 != cur) { atomicAdd(&pooled[cur * 64 + lane], acc); if (lane == 0) atomicAdd(&cnt[cur], c); acc = 0.f; c = 0.f; cur = b0; }
        acc += v0; c += 1.f;
        if (b1 != cur) { atomicAdd(&pooled[cur * 64 + lane], acc); if (lane == 0) atomicAdd(&cnt[cur], c); acc = 0.f; c = 0.f; cur = b1; }
        acc += v1; c += 1.f;
        if (b2 != cur) { atomicAdd(&pooled[cur * 64 + lane], acc); if (lane == 0) atomicAdd(&cnt[cur], c); acc = 0.f; c = 0.f; cur = b2; }
        acc += v2; c += 1.f;
        if (b3 != cur) { atomicAdd(&pooled[cur * 64 + lane], acc); if (lane == 0) atomicAdd(&cnt[cur], c); acc = 0.f; c = 0.f; cur = b3; }
        acc += v3; c += 1.f;
    }
    for (; i < end; i++) {
        int b = batch[i];
        if (b != cur) { atomicAdd(&pooled[cur * 64 + lane], acc); if (lane == 0) atomicAdd(&cnt[cur], c); acc = 0.f; c = 0.f; cur = b; }
        acc += fmaxf(0.f, fmaf((float)pre[(long long)i * 64 + lane], A, B)); c += 1.f;
    }
    atomicAdd(&pooled[cur * 64 + lane], acc);
    if (lane == 0) atomicAdd(&cnt[cur], c);
}

// ---------------- final linear ----------------
__global__ void final_kernel(const float* __restrict__ pooled, const float* __restrict__ cnt,
                             const float* __restrict__ fcW, const float* __restrict__ fcb,
                             float* __restrict__ out) {
    int t = blockIdx.x * blockDim.x + threadIdx.x;
    if (t >= B_GRAPHS * 10) return;
    int b = t / 10, j = t % 10;
    float inv = 1.0f / fmaxf(cnt[b], 1.0f);
    float acc = fcb[j];
#pragma unroll
    for (int f = 0; f < 64; f++) acc += pooled[b * 64 + f] * inv * fcW[f * 10 + j];
    out[t] = acc;
}

extern "C" void kernel_launch(void* const* d_in, const int* in_sizes, int n_in,
                              void* d_out, int out_size, void* d_ws, size_t ws_size,
                              hipStream_t stream) {
    const float* x  = (const float*)d_in[0];
    const int* ei   = (const int*)d_in[1];
    const int* batch= (const int*)d_in[2];
    const float* W1 = (const float*)d_in[3];  const float* b1 = (const float*)d_in[4];
    const float* g1 = (const float*)d_in[5];  const float* be1= (const float*)d_in[6];
    const float* W2 = (const float*)d_in[7];  const float* b2 = (const float*)d_in[8];
    const float* g2 = (const float*)d_in[9];  const float* be2= (const float*)d_in[10];
    const float* W3 = (const float*)d_in[11]; const float* b3 = (const float*)d_in[12];
    const float* g3 = (const float*)d_in[13]; const float* be3= (const float*)d_in[14];
    const float* fcW= (const float*)d_in[15]; const float* fcb= (const float*)d_in[16];
    float* out = (float*)d_out;

    const int* row = ei;
    const int* col = ei + N_EDGES;

    // workspace layout — zero region first (one memset): bucket_cnt, pooled, cnt
    char* wp = (char*)d_ws;
    int*   bucket_cnt = (int*)wp;                wp += NBUCK * 4;
    float* pooled     = (float*)wp;              wp += 64 * 64 * 4;
    float* cnt        = (float*)wp;              wp += 64 * 4;
    const size_t ZERO_BYTES = NBUCK * 4 + 64 * 64 * 4 + 64 * 4;
    float* dis        = (float*)wp;              wp += N_NODES * 4;
    int*   deg_i      = (int*)wp;                wp += N_NODES * 4;
    int*   row_ptr    = (int*)wp;                wp += N_NODES * 4;
    int*   bucket_base= (int*)wp;                wp += NBUCK * 4;
    int*   bucket_cur = (int*)wp;                wp += NBUCK * 4;
    int*   sorted_row = (int*)wp;                wp += (size_t)N_EDGES * 4;
    unsigned* part_edges = (unsigned*)wp;        wp += (size_t)N_EDGES * 4;
    double* part_s    = (double*)wp;             wp += (size_t)NBMAX * 64 * 8;
    double* part_q    = (double*)wp;             wp += (size_t)NBMAX * 64 * 8;
    float* bn_mean    = (float*)wp;              wp += 64 * 4;
    float* bn_rstd    = (float*)wp;              wp += 64 * 4;
    _Float16* xs4h    = (_Float16*)wp;           wp += (size_t)N_NODES * 4 * 2;
    _Float16* PRE     = (_Float16*)wp;           wp += (size_t)N_NODES * 64 * 2;  // matmul out (fp16)
    _Float16* Hh      = (_Float16*)wp;           wp += (size_t)N_NODES * 32 * 2;  // h1/h2 (fp16, pre-scaled)

    const int BS = 256;

    // ---- one memset for all zero-init state
    hipMemsetAsync(bucket_cnt, 0, ZERO_BYTES, stream);

    // ---- CSR build: bucketed two-phase + per-node sort (deterministic); emits xs4h
    part_hist_kernel<<<NB_PART, 256, 0, stream>>>(col, bucket_cnt);
    part_scan_kernel<<<1, NBUCK, 0, stream>>>(bucket_cnt, bucket_base, bucket_cur);
    part_scatter_kernel<<<NB_PART, 256, 0, stream>>>(row, col, bucket_cur, part_edges);
    csr_build_kernel<<<NBUCK, 256, 0, stream>>>(bucket_base, part_edges, row_ptr, deg_i, dis, sorted_row, x, xs4h);

    // ---- layer 1: fused gather(F=4)+matmul 3->16  (NPB=256 -> 391 blocks)
    const int NB1 = cdiv(N_NODES, 256);
    gather_mm_kernel<3, 16, 4><<<NB1, 256, 0, stream>>>(
        row_ptr, deg_i, sorted_row, dis, xs4h, W1, b1, PRE, part_s, part_q);
    bn_finalize_kernel<<<16, 256, 0, stream>>>(part_s, part_q, NB1, bn_mean, bn_rstd);
    bn_relu_kernel<16, true><<<cdiv((long long)N_NODES * 4, BS), BS, 0, stream>>>(
        PRE, bn_mean, bn_rstd, g1, be1, dis, Hh);  // Hh = h1 * dis (fp16)

    // ---- layer 2: fused gather(F=16)+matmul 16->32  (NPB=64 -> 1563 blocks)
    const int NB2 = cdiv(N_NODES, 64);
    gather_mm_kernel<16, 32, 16><<<NB2, 256, 0, stream>>>(
        row_ptr, deg_i, sorted_row, dis, Hh, W2, b2, PRE, part_s, part_q);
    bn_finalize_kernel<<<32, 256, 0, stream>>>(part_s, part_q, NB2, bn_mean, bn_rstd);
    bn_relu_kernel<32, true><<<cdiv((long long)N_NODES * 8, BS), BS, 0, stream>>>(
        PRE, bn_mean, bn_rstd, g2, be2, dis, Hh);  // Hh = h2 * dis (fp16)

    // ---- layer 3: fused gather(F=32)+matmul 32->64  (NPB=32 -> 3125 blocks)
    const int NB3 = cdiv(N_NODES, 32);
    gather_mm_kernel<32, 64, 32><<<NB3, 256, 0, stream>>>(
        row_ptr, deg_i, sorted_row, dis, Hh, W3, b3, PRE, part_s, part_q);
    bn_finalize_kernel<<<64, 256, 0, stream>>>(part_s, part_q, NB3, bn_mean, bn_rstd);

    // ---- pool (fused BN3+ReLU) + fc
    pool_kernel<<<cdiv((long long)cdiv(N_NODES, POOL_CHUNK) * 64, BS), BS, 0, stream>>>(
        PRE, batch, bn_mean, bn_rstd, g3, be3, pooled, cnt);
    final_kernel<<<1, B_GRAPHS * 10, 0, stream>>>(pooled, cnt, fcW, fcb, out);
}

// Round 18
// 287.534 us; speedup vs baseline: 1.2046x; 1.2046x over previous
//
#include <hip/hip_runtime.h>

#define N_NODES 100000
#define N_EDGES 1600000
#define B_GRAPHS 64
#define BN_EPS 1e-5
#define NBMAX 3200    // max per-layer stats-partial blocks (L3 uses 3125)

#define NBUCK 256
#define BUCK_NODES 392   // 256*392 = 100352 >= N_NODES; 392 < 512 -> 9-bit local id
#define PART_CHUNK 4096
#define NB_PART 391      // cdiv(N_EDGES, PART_CHUNK)

#define FPSCALE 262144.0f        // 2^18 fixed-point scale
#define FPINV   3.814697265625e-6f  // 2^-18

typedef _Float16 half4_t __attribute__((ext_vector_type(4)));

static inline int cdiv(long long a, int b) { return (int)((a + b - 1) / b); }

__device__ __forceinline__ int fxp(float v) { return __float2int_rn(v * FPSCALE); }

// ---------------- phase 1: bucket histogram of col ----------------
__global__ void part_hist_kernel(const int* __restrict__ col, int* __restrict__ bucket_cnt) {
    __shared__ int h[NBUCK];
    for (int i = threadIdx.x; i < NBUCK; i += 256) h[i] = 0;
    __syncthreads();
    long long ebase = (long long)blockIdx.x * PART_CHUNK;
    int n = (N_EDGES - ebase < PART_CHUNK) ? (int)(N_EDGES - ebase) : PART_CHUNK;
    for (int i = threadIdx.x; i < n; i += 256)
        atomicAdd(&h[col[ebase + i] / BUCK_NODES], 1);
    __syncthreads();
    for (int i = threadIdx.x; i < NBUCK; i += 256)
        if (h[i]) atomicAdd(&bucket_cnt[i], h[i]);
}

// ---------------- phase 2: scan bucket counts -> base & cursor ----------------
__global__ void part_scan_kernel(const int* __restrict__ bucket_cnt, int* __restrict__ bucket_base,
                                 int* __restrict__ bucket_cur) {
    __shared__ int s[NBUCK];
    int t = threadIdx.x;
    int v = bucket_cnt[t];
    s[t] = v;
    __syncthreads();
    for (int off = 1; off < NBUCK; off <<= 1) {
        int u = (t >= off) ? s[t - off] : 0;
        __syncthreads();
        s[t] += u;
        __syncthreads();
    }
    bucket_base[t] = s[t] - v;  // exclusive
    bucket_cur[t] = s[t] - v;
}

// ---------------- phase 3: partition edges; pack (row,local_col) into one uint ----------------
// Edge order is nondeterministic; downstream sums are order-INDEPENDENT (int accumulation),
// so this is harmless.
__global__ void part_scatter_kernel(const int* __restrict__ row, const int* __restrict__ col,
                                    int* __restrict__ bucket_cur, unsigned* __restrict__ part_edges) {
    __shared__ int h[NBUCK];
    __shared__ int base_s[NBUCK];
    __shared__ int cur_s[NBUCK];
    long long ebase = (long long)blockIdx.x * PART_CHUNK;
    int n = (N_EDGES - ebase < PART_CHUNK) ? (int)(N_EDGES - ebase) : PART_CHUNK;
    for (int i = threadIdx.x; i < NBUCK; i += 256) h[i] = 0;
    __syncthreads();
    for (int i = threadIdx.x; i < n; i += 256)
        atomicAdd(&h[col[ebase + i] / BUCK_NODES], 1);
    __syncthreads();
    for (int i = threadIdx.x; i < NBUCK; i += 256) {
        int c = h[i];
        base_s[i] = c ? atomicAdd(&bucket_cur[i], c) : 0;
        cur_s[i] = 0;
    }
    __syncthreads();
    for (int i = threadIdx.x; i < n; i += 256) {
        int r = row[ebase + i], c = col[ebase + i];
        int bkt = c / BUCK_NODES;
        int p = base_s[bkt] + atomicAdd(&cur_s[bkt], 1);
        part_edges[p] = ((unsigned)r << 9) | (unsigned)(c - bkt * BUCK_NODES);
    }
}

// ---------------- phase 4: per-bucket CSR build + fused scale_x (fp16, pad 3->4) ----------------
__global__ void csr_build_kernel(const int* __restrict__ bucket_base, const unsigned* __restrict__ part_edges,
                                 int* __restrict__ row_ptr, int* __restrict__ deg,
                                 float* __restrict__ dis, int* __restrict__ sorted_row,
                                 const float* __restrict__ x, _Float16* __restrict__ xs4) {
    __shared__ int hist[BUCK_NODES];  // histogram, then reused as scatter cursors
    __shared__ int tsum[256];
    int b = blockIdx.x;
    int t = threadIdx.x;
    int nbase = b * BUCK_NODES;
    int ebase = bucket_base[b];
    int eend = (b == NBUCK - 1) ? N_EDGES : bucket_base[b + 1];
    int ne = eend - ebase;
    for (int i = t; i < BUCK_NODES; i += 256) hist[i] = 0;
    __syncthreads();
    for (int i = t; i < ne; i += 256)
        atomicAdd(&hist[part_edges[ebase + i] & 511u], 1);
    __syncthreads();
    int a0 = 0, a1 = 0;
    if (t < BUCK_NODES / 2) { a0 = hist[2 * t]; a1 = hist[2 * t + 1]; tsum[t] = a0 + a1; }
    else tsum[t] = 0;
    __syncthreads();
    for (int off = 1; off < 256; off <<= 1) {
        int u = (t >= off) ? tsum[t - off] : 0;
        __syncthreads();
        tsum[t] += u;
        __syncthreads();
    }
    if (t < BUCK_NODES / 2) {
        int excl = tsum[t] - (a0 + a1);
        hist[2 * t] = excl;
        hist[2 * t + 1] = excl + a0;
        int n0 = nbase + 2 * t, n1 = n0 + 1;
        if (n0 < N_NODES) {
            row_ptr[n0] = ebase + excl;
            deg[n0] = a0;
            dis[n0] = rsqrtf((float)a0 + 1.0f);
        }
        if (n1 < N_NODES) {
            row_ptr[n1] = ebase + excl + a0;
            deg[n1] = a1;
            dis[n1] = rsqrtf((float)a1 + 1.0f);
        }
    }
    __syncthreads();
    for (int i = t; i < ne; i += 256) {
        unsigned e = part_edges[ebase + i];
        int p = atomicAdd(&hist[e & 511u], 1);
        sorted_row[ebase + p] = (int)(e >> 9);
    }
    // fused scale_x for this bucket's nodes
    for (int i = t; i < BUCK_NODES; i += 256) {
        int n = nbase + i;
        if (n < N_NODES) {
            float d = dis[n];
            half4_t v;
            v.x = (_Float16)(x[n * 3 + 0] * d);
            v.y = (_Float16)(x[n * 3 + 1] * d);
            v.z = (_Float16)(x[n * 3 + 2] * d);
            v.w = (_Float16)0.f;
            ((half4_t*)xs4)[n] = v;
        }
    }
}

// ---------------- FUSED: CSR gather (f16x4, x8 unroll, INT32 fixed-point accum = order-independent)
//                  -> LDS -> matmul -> fp16 pre + fp64 stats ----------------
template <int IN, int OUT, int INSTRIDE>
__global__ void gather_mm_kernel(const int* __restrict__ row_ptr, const int* __restrict__ deg,
                                 const int* __restrict__ sorted_row, const float* __restrict__ dis,
                                 const _Float16* __restrict__ hs, const float* __restrict__ W,
                                 const float* __restrict__ b, _Float16* __restrict__ pre,
                                 double* __restrict__ part_s, double* __restrict__ part_q) {
    const int LPN = INSTRIDE / 4;  // lanes per node
    const int NPW = 64 / LPN;      // nodes per wave
    const int NPB = 4 * NPW;       // nodes per block (256 threads)
    __shared__ float lds_agg[1024];  // NPB * INSTRIDE == 1024 floats always
    __shared__ float Ws[IN * OUT];
    __shared__ double s_s[256];
    __shared__ double s_q[256];
    int tid = threadIdx.x;
    for (int k = tid; k < IN * OUT; k += 256) Ws[k] = W[k];

    // ---- gather phase: int32 fixed-point accumulation (associative -> deterministic
    //      for ANY edge order produced by the nondeterministic CSR scatter)
    int wv = tid >> 6, lane = tid & 63;
    int jn = wv * NPW + lane / LPN;  // node index within block
    int p = lane % LPN;              // feature-quad index
    int n = blockIdx.x * NPB + jn;
    if (n < N_NODES) {
        int start = row_ptr[n];
        int d = deg[n];
        const int* sr = sorted_row + start;
        const half4_t* h4 = (const half4_t*)hs;
        half4_t v = h4[(long long)n * LPN + p];
        int acc0 = fxp((float)v.x), acc1 = fxp((float)v.y), acc2 = fxp((float)v.z), acc3 = fxp((float)v.w);
        int j = 0;
        for (; j + 8 <= d; j += 8) {
            int r0 = sr[j], r1 = sr[j + 1], r2 = sr[j + 2], r3 = sr[j + 3];
            int r4 = sr[j + 4], r5 = sr[j + 5], r6 = sr[j + 6], r7 = sr[j + 7];
            half4_t a0 = h4[(long long)r0 * LPN + p];
            half4_t a1 = h4[(long long)r1 * LPN + p];
            half4_t a2 = h4[(long long)r2 * LPN + p];
            half4_t a3 = h4[(long long)r3 * LPN + p];
            half4_t a4 = h4[(long long)r4 * LPN + p];
            half4_t a5 = h4[(long long)r5 * LPN + p];
            half4_t a6 = h4[(long long)r6 * LPN + p];
            half4_t a7 = h4[(long long)r7 * LPN + p];
            acc0 += ((fxp((float)a0.x) + fxp((float)a1.x)) + (fxp((float)a2.x) + fxp((float)a3.x))) +
                    ((fxp((float)a4.x) + fxp((float)a5.x)) + (fxp((float)a6.x) + fxp((float)a7.x)));
            acc1 += ((fxp((float)a0.y) + fxp((float)a1.y)) + (fxp((float)a2.y) + fxp((float)a3.y))) +
                    ((fxp((float)a4.y) + fxp((float)a5.y)) + (fxp((float)a6.y) + fxp((float)a7.y)));
            acc2 += ((fxp((float)a0.z) + fxp((float)a1.z)) + (fxp((float)a2.z) + fxp((float)a3.z))) +
                    ((fxp((float)a4.z) + fxp((float)a5.z)) + (fxp((float)a6.z) + fxp((float)a7.z)));
            acc3 += ((fxp((float)a0.w) + fxp((float)a1.w)) + (fxp((float)a2.w) + fxp((float)a3.w))) +
                    ((fxp((float)a4.w) + fxp((float)a5.w)) + (fxp((float)a6.w) + fxp((float)a7.w)));
        }
        for (; j < d; j++) {
            half4_t a = h4[(long long)sr[j] * LPN + p];
            acc0 += fxp((float)a.x);
            acc1 += fxp((float)a.y);
            acc2 += fxp((float)a.z);
            acc3 += fxp((float)a.w);
        }
        float dn = dis[n] * FPINV;
        float* dst = &lds_agg[(jn * LPN + p) * 4];
        dst[0] = dn * (float)acc0;
        dst[1] = dn * (float)acc1;
        dst[2] = dn * (float)acc2;
        dst[3] = dn * (float)acc3;
    }
    __syncthreads();

    // ---- matmul + stats phase (deterministic: fixed order over deterministic agg)
    const int NG = 256 / OUT;  // node groups
    int o = tid % OUT;
    int g = tid / OUT;
    float bo = b[o];
    double my_s = 0.0, my_q = 0.0;
    for (int j = g; j < NPB; j += NG) {
        int nn = blockIdx.x * NPB + j;
        if (nn < N_NODES) {
            float acc = bo;
#pragma unroll
            for (int k = 0; k < IN; k++) acc += lds_agg[j * INSTRIDE + k] * Ws[k * OUT + o];
            _Float16 q = (_Float16)acc;
            pre[(long long)nn * OUT + o] = q;
            float fq = (float)q;  // stats on quantized values
            my_s += (double)fq;
            my_q += (double)fq * (double)fq;
        }
    }
    s_s[tid] = my_s;
    s_q[tid] = my_q;
    __syncthreads();
    if (tid < OUT) {
        double ts = 0.0, tq = 0.0;
        for (int k = tid; k < 256; k += OUT) { ts += s_s[k]; tq += s_q[k]; }
        part_s[(long long)tid * NBMAX + blockIdx.x] = ts;
        part_q[(long long)tid * NBMAX + blockIdx.x] = tq;
    }
}

// ---------------- finalize BN stats: one block per feature, variable #partials ----------------
__global__ void bn_finalize_kernel(const double* __restrict__ part_s, const double* __restrict__ part_q,
                                   int nb, float* __restrict__ bn_mean, float* __restrict__ bn_rstd) {
    __shared__ double s_s[256];
    __shared__ double s_q[256];
    int o = blockIdx.x;
    int t = threadIdx.x;
    double ms = 0.0, mq = 0.0;
    for (int k = t; k < nb; k += 256) {
        ms += part_s[(long long)o * NBMAX + k];
        mq += part_q[(long long)o * NBMAX + k];
    }
    s_s[t] = ms;
    s_q[t] = mq;
    __syncthreads();
    for (int off = 128; off > 0; off >>= 1) {
        if (t < off) { s_s[t] += s_s[t + off]; s_q[t] += s_q[t + off]; }
        __syncthreads();
    }
    if (t == 0) {
        double mean = s_s[0] / (double)N_NODES;
        double var = s_q[0] / (double)N_NODES - mean * mean;
        bn_mean[o] = (float)mean;
        bn_rstd[o] = (float)(1.0 / sqrt(var + BN_EPS));
    }
}

// ---------------- BN apply + ReLU, half4-vectorized; fp16 in, fp16 out ----------------
template <int F, bool SCALE>
__global__ void bn_relu_kernel(const _Float16* __restrict__ pre, const float* __restrict__ bn_mean,
                               const float* __restrict__ bn_rstd, const float* __restrict__ g,
                               const float* __restrict__ be, const float* __restrict__ dis,
                               _Float16* __restrict__ out) {
    const int GP = F / 4;  // half4 groups per node
    int t = blockIdx.x * blockDim.x + threadIdx.x;
    const int total = N_NODES * GP;
    if (t >= total) return;
    int gi = t % GP;
    int f0 = gi * 4;
    half4_t v = ((const half4_t*)pre)[t];
    float d = SCALE ? dis[t / GP] : 1.0f;
    half4_t o;
#pragma unroll
    for (int k = 0; k < 4; k++) {
        int f = f0 + k;
        float y = ((float)v[k] - bn_mean[f]) * bn_rstd[f] * g[f] + be[f];
        y = y > 0.f ? y : 0.f;
        if (SCALE) y *= d;
        o[k] = (_Float16)y;
    }
    ((half4_t*)out)[t] = o;
}

// ---------------- mean pool with FUSED BN3+ReLU (reads fp16 PRE directly) ----------------
#define POOL_CHUNK 32
__global__ void pool_kernel(const _Float16* __restrict__ pre, const int* __restrict__ batch,
                            const float* __restrict__ bn_mean, const float* __restrict__ bn_rstd,
                            const float* __restrict__ g, const float* __restrict__ be,
                            float* __restrict__ pooled, float* __restrict__ cnt) {
    int wave = (blockIdx.x * blockDim.x + threadIdx.x) >> 6;
    int lane = threadIdx.x & 63;  // feature index
    int start = wave * POOL_CHUNK;
    if (start >= N_NODES) return;
    int end = start + POOL_CHUNK;
    if (end > N_NODES) end = N_NODES;
    float A = bn_rstd[lane] * g[lane];
    float B = be[lane] - bn_mean[lane] * A;
    int cur = batch[start];  // wave-uniform -> scalar load
    float acc = 0.f;
    float c = 0.f;
    int i = start;
    for (; i + 4 <= end; i += 4) {
        int b0 = batch[i], b1 = batch[i + 1], b2 = batch[i + 2], b3 = batch[i + 3];
        float v0 = fmaxf(0.f, fmaf((float)pre[(long long)i * 64 + lane], A, B));
        float v1 = fmaxf(0.f, fmaf((float)pre[(long long)(i + 1) * 64 + lane], A, B));
        float v2 = fmaxf(0.f, fmaf((float)pre[(long long)(i + 2) * 64 + lane], A, B));
        float v3 = fmaxf(0.f, fmaf((float)pre[(long long)(i + 3) * 64 + lane], A, B));
        if (b0 != cur) { atomicAdd(&pooled[cur * 64 + lane], acc); if (lane == 0) atomicAdd(&cnt[cur], c); acc = 0.f; c = 0.f; cur = b0; }
        acc += v0; c += 1.f;
        if (b1 != cur) { atomicAdd(&pooled[cur * 64 + lane], acc); if (lane == 0) atomicAdd(&cnt[cur], c); acc = 0.f; c = 0.f; cur = b1; }
        acc += v1; c += 1.f;
        if (b2 != cur) { atomicAdd(&pooled[cur * 64 + lane], acc); if (lane == 0) atomicAdd(&cnt[cur], c); acc = 0.f; c = 0.f; cur = b2; }
        acc += v2; c += 1.f;
        if (b3 != cur) { atomicAdd(&pooled[cur * 64 + lane], acc); if (lane == 0) atomicAdd(&cnt[cur], c); acc = 0.f; c = 0.f; cur = b3; }
        acc += v3; c += 1.f;
    }
    for (; i < end; i++) {
        int b = batch[i];
        if (b != cur) { atomicAdd(&pooled[cur * 64 + lane], acc); if (lane == 0) atomicAdd(&cnt[cur], c); acc = 0.f; c = 0.f; cur = b; }
        acc += fmaxf(0.f, fmaf((float)pre[(long long)i * 64 + lane], A, B)); c += 1.f;
    }
    atomicAdd(&pooled[cur * 64 + lane], acc);
    if (lane == 0) atomicAdd(&cnt[cur], c);
}

// ---------------- final linear ----------------
__global__ void final_kernel(const float* __restrict__ pooled, const float* __restrict__ cnt,
                             const float* __restrict__ fcW, const float* __restrict__ fcb,
                             float* __restrict__ out) {
    int t = blockIdx.x * blockDim.x + threadIdx.x;
    if (t >= B_GRAPHS * 10) return;
    int b = t / 10, j = t % 10;
    float inv = 1.0f / fmaxf(cnt[b], 1.0f);
    float acc = fcb[j];
#pragma unroll
    for (int f = 0; f < 64; f++) acc += pooled[b * 64 + f] * inv * fcW[f * 10 + j];
    out[t] = acc;
}

extern "C" void kernel_launch(void* const* d_in, const int* in_sizes, int n_in,
                              void* d_out, int out_size, void* d_ws, size_t ws_size,
                              hipStream_t stream) {
    const float* x  = (const float*)d_in[0];
    const int* ei   = (const int*)d_in[1];
    const int* batch= (const int*)d_in[2];
    const float* W1 = (const float*)d_in[3];  const float* b1 = (const float*)d_in[4];
    const float* g1 = (const float*)d_in[5];  const float* be1= (const float*)d_in[6];
    const float* W2 = (const float*)d_in[7];  const float* b2 = (const float*)d_in[8];
    const float* g2 = (const float*)d_in[9];  const float* be2= (const float*)d_in[10];
    const float* W3 = (const float*)d_in[11]; const float* b3 = (const float*)d_in[12];
    const float* g3 = (const float*)d_in[13]; const float* be3= (const float*)d_in[14];
    const float* fcW= (const float*)d_in[15]; const float* fcb= (const float*)d_in[16];
    float* out = (float*)d_out;

    const int* row = ei;
    const int* col = ei + N_EDGES;

    // workspace layout — zero region first (one memset): bucket_cnt, pooled, cnt
    char* wp = (char*)d_ws;
    int*   bucket_cnt = (int*)wp;                wp += NBUCK * 4;
    float* pooled     = (float*)wp;              wp += 64 * 64 * 4;
    float* cnt        = (float*)wp;              wp += 64 * 4;
    const size_t ZERO_BYTES = NBUCK * 4 + 64 * 64 * 4 + 64 * 4;
    float* dis        = (float*)wp;              wp += N_NODES * 4;
    int*   deg_i      = (int*)wp;                wp += N_NODES * 4;
    int*   row_ptr    = (int*)wp;                wp += N_NODES * 4;
    int*   bucket_base= (int*)wp;                wp += NBUCK * 4;
    int*   bucket_cur = (int*)wp;                wp += NBUCK * 4;
    int*   sorted_row = (int*)wp;                wp += (size_t)N_EDGES * 4;
    unsigned* part_edges = (unsigned*)wp;        wp += (size_t)N_EDGES * 4;
    double* part_s    = (double*)wp;             wp += (size_t)NBMAX * 64 * 8;
    double* part_q    = (double*)wp;             wp += (size_t)NBMAX * 64 * 8;
    float* bn_mean    = (float*)wp;              wp += 64 * 4;
    float* bn_rstd    = (float*)wp;              wp += 64 * 4;
    _Float16* xs4h    = (_Float16*)wp;           wp += (size_t)N_NODES * 4 * 2;
    _Float16* PRE     = (_Float16*)wp;           wp += (size_t)N_NODES * 64 * 2;  // matmul out (fp16)
    _Float16* Hh      = (_Float16*)wp;           wp += (size_t)N_NODES * 32 * 2;  // h1/h2 (fp16, pre-scaled)

    const int BS = 256;

    // ---- one memset for all zero-init state
    hipMemsetAsync(bucket_cnt, 0, ZERO_BYTES, stream);

    // ---- CSR build: bucketed two-phase (fast, order-nondeterministic — harmless); emits xs4h
    part_hist_kernel<<<NB_PART, 256, 0, stream>>>(col, bucket_cnt);
    part_scan_kernel<<<1, NBUCK, 0, stream>>>(bucket_cnt, bucket_base, bucket_cur);
    part_scatter_kernel<<<NB_PART, 256, 0, stream>>>(row, col, bucket_cur, part_edges);
    csr_build_kernel<<<NBUCK, 256, 0, stream>>>(bucket_base, part_edges, row_ptr, deg_i, dis, sorted_row, x, xs4h);

    // ---- layer 1: fused gather(F=4)+matmul 3->16  (NPB=256 -> 391 blocks)
    const int NB1 = cdiv(N_NODES, 256);
    gather_mm_kernel<3, 16, 4><<<NB1, 256, 0, stream>>>(
        row_ptr, deg_i, sorted_row, dis, xs4h, W1, b1, PRE, part_s, part_q);
    bn_finalize_kernel<<<16, 256, 0, stream>>>(part_s, part_q, NB1, bn_mean, bn_rstd);
    bn_relu_kernel<16, true><<<cdiv((long long)N_NODES * 4, BS), BS, 0, stream>>>(
        PRE, bn_mean, bn_rstd, g1, be1, dis, Hh);  // Hh = h1 * dis (fp16)

    // ---- layer 2: fused gather(F=16)+matmul 16->32  (NPB=64 -> 1563 blocks)
    const int NB2 = cdiv(N_NODES, 64);
    gather_mm_kernel<16, 32, 16><<<NB2, 256, 0, stream>>>(
        row_ptr, deg_i, sorted_row, dis, Hh, W2, b2, PRE, part_s, part_q);
    bn_finalize_kernel<<<32, 256, 0, stream>>>(part_s, part_q, NB2, bn_mean, bn_rstd);
    bn_relu_kernel<32, true><<<cdiv((long long)N_NODES * 8, BS), BS, 0, stream>>>(
        PRE, bn_mean, bn_rstd, g2, be2, dis, Hh);  // Hh = h2 * dis (fp16)

    // ---- layer 3: fused gather(F=32)+matmul 32->64  (NPB=32 -> 3125 blocks)
    const int NB3 = cdiv(N_NODES, 32);
    gather_mm_kernel<32, 64, 32><<<NB3, 256, 0, stream>>>(
        row_ptr, deg_i, sorted_row, dis, Hh, W3, b3, PRE, part_s, part_q);
    bn_finalize_kernel<<<64, 256, 0, stream>>>(part_s, part_q, NB3, bn_mean, bn_rstd);

    // ---- pool (fused BN3+ReLU) + fc
    pool_kernel<<<cdiv((long long)cdiv(N_NODES, POOL_CHUNK) * 64, BS), BS, 0, stream>>>(
        PRE, batch, bn_mean, bn_rstd, g3, be3, pooled, cnt);
    final_kernel<<<1, B_GRAPHS * 10, 0, stream>>>(pooled, cnt, fcW, fcb, out);
}

// Round 19
// 280.735 us; speedup vs baseline: 1.2338x; 1.0242x over previous
//
#include <hip/hip_runtime.h>

#define N_NODES 100000
#define N_EDGES 1600000
#define B_GRAPHS 64
#define BN_EPS 1e-5
#define NBMAX 3200    // max per-layer stats-partial blocks (L3 uses 3125)

#define NBUCK 256
#define BUCK_NODES 392   // 256*392 = 100352 >= N_NODES; 392 < 512 -> 9-bit local id
#define PART_CHUNK 4096
#define NB_PART 391      // cdiv(N_EDGES, PART_CHUNK)

#define QSCALE 2048.0f            // 2^11 int16 fixed-point scale
#define QINV   4.8828125e-4f      // 2^-11

typedef _Float16 half4_t __attribute__((ext_vector_type(4)));
typedef short short4_t __attribute__((ext_vector_type(4)));

static inline int cdiv(long long a, int b) { return (int)((a + b - 1) / b); }

__device__ __forceinline__ short q16(float v) {
    int q = __float2int_rn(v * QSCALE);
    q = q > 32767 ? 32767 : (q < -32768 ? -32768 : q);
    return (short)q;
}

// ---------------- phase 1: bucket histogram of col ----------------
__global__ void part_hist_kernel(const int* __restrict__ col, int* __restrict__ bucket_cnt) {
    __shared__ int h[NBUCK];
    for (int i = threadIdx.x; i < NBUCK; i += 256) h[i] = 0;
    __syncthreads();
    long long ebase = (long long)blockIdx.x * PART_CHUNK;
    int n = (N_EDGES - ebase < PART_CHUNK) ? (int)(N_EDGES - ebase) : PART_CHUNK;
    for (int i = threadIdx.x; i < n; i += 256)
        atomicAdd(&h[col[ebase + i] / BUCK_NODES], 1);
    __syncthreads();
    for (int i = threadIdx.x; i < NBUCK; i += 256)
        if (h[i]) atomicAdd(&bucket_cnt[i], h[i]);
}

// ---------------- phase 2: scan bucket counts -> base & cursor ----------------
__global__ void part_scan_kernel(const int* __restrict__ bucket_cnt, int* __restrict__ bucket_base,
                                 int* __restrict__ bucket_cur) {
    __shared__ int s[NBUCK];
    int t = threadIdx.x;
    int v = bucket_cnt[t];
    s[t] = v;
    __syncthreads();
    for (int off = 1; off < NBUCK; off <<= 1) {
        int u = (t >= off) ? s[t - off] : 0;
        __syncthreads();
        s[t] += u;
        __syncthreads();
    }
    bucket_base[t] = s[t] - v;  // exclusive
    bucket_cur[t] = s[t] - v;
}

// ---------------- phase 3: partition edges; pack (row,local_col) into one uint ----------------
// Edge order nondeterministic; downstream sums are order-INDEPENDENT (int accumulation).
__global__ void part_scatter_kernel(const int* __restrict__ row, const int* __restrict__ col,
                                    int* __restrict__ bucket_cur, unsigned* __restrict__ part_edges) {
    __shared__ int h[NBUCK];
    __shared__ int base_s[NBUCK];
    __shared__ int cur_s[NBUCK];
    long long ebase = (long long)blockIdx.x * PART_CHUNK;
    int n = (N_EDGES - ebase < PART_CHUNK) ? (int)(N_EDGES - ebase) : PART_CHUNK;
    for (int i = threadIdx.x; i < NBUCK; i += 256) h[i] = 0;
    __syncthreads();
    for (int i = threadIdx.x; i < n; i += 256)
        atomicAdd(&h[col[ebase + i] / BUCK_NODES], 1);
    __syncthreads();
    for (int i = threadIdx.x; i < NBUCK; i += 256) {
        int c = h[i];
        base_s[i] = c ? atomicAdd(&bucket_cur[i], c) : 0;
        cur_s[i] = 0;
    }
    __syncthreads();
    for (int i = threadIdx.x; i < n; i += 256) {
        int r = row[ebase + i], c = col[ebase + i];
        int bkt = c / BUCK_NODES;
        int p = base_s[bkt] + atomicAdd(&cur_s[bkt], 1);
        part_edges[p] = ((unsigned)r << 9) | (unsigned)(c - bkt * BUCK_NODES);
    }
}

// ---------------- phase 4: per-bucket CSR build + fused scale_x (int16 fixed-point, pad 3->4) ----------------
__global__ void csr_build_kernel(const int* __restrict__ bucket_base, const unsigned* __restrict__ part_edges,
                                 int* __restrict__ row_ptr, int* __restrict__ deg,
                                 float* __restrict__ dis, int* __restrict__ sorted_row,
                                 const float* __restrict__ x, short* __restrict__ xs4) {
    __shared__ int hist[BUCK_NODES];  // histogram, then reused as scatter cursors
    __shared__ int tsum[256];
    int b = blockIdx.x;
    int t = threadIdx.x;
    int nbase = b * BUCK_NODES;
    int ebase = bucket_base[b];
    int eend = (b == NBUCK - 1) ? N_EDGES : bucket_base[b + 1];
    int ne = eend - ebase;
    for (int i = t; i < BUCK_NODES; i += 256) hist[i] = 0;
    __syncthreads();
    for (int i = t; i < ne; i += 256)
        atomicAdd(&hist[part_edges[ebase + i] & 511u], 1);
    __syncthreads();
    int a0 = 0, a1 = 0;
    if (t < BUCK_NODES / 2) { a0 = hist[2 * t]; a1 = hist[2 * t + 1]; tsum[t] = a0 + a1; }
    else tsum[t] = 0;
    __syncthreads();
    for (int off = 1; off < 256; off <<= 1) {
        int u = (t >= off) ? tsum[t - off] : 0;
        __syncthreads();
        tsum[t] += u;
        __syncthreads();
    }
    if (t < BUCK_NODES / 2) {
        int excl = tsum[t] - (a0 + a1);
        hist[2 * t] = excl;
        hist[2 * t + 1] = excl + a0;
        int n0 = nbase + 2 * t, n1 = n0 + 1;
        if (n0 < N_NODES) {
            row_ptr[n0] = ebase + excl;
            deg[n0] = a0;
            dis[n0] = rsqrtf((float)a0 + 1.0f);
        }
        if (n1 < N_NODES) {
            row_ptr[n1] = ebase + excl + a0;
            deg[n1] = a1;
            dis[n1] = rsqrtf((float)a1 + 1.0f);
        }
    }
    __syncthreads();
    for (int i = t; i < ne; i += 256) {
        unsigned e = part_edges[ebase + i];
        int p = atomicAdd(&hist[e & 511u], 1);
        sorted_row[ebase + p] = (int)(e >> 9);
    }
    // fused scale_x (int16 fixed-point) for this bucket's nodes
    for (int i = t; i < BUCK_NODES; i += 256) {
        int n = nbase + i;
        if (n < N_NODES) {
            float d = dis[n];
            short4_t v;
            v.x = q16(x[n * 3 + 0] * d);
            v.y = q16(x[n * 3 + 1] * d);
            v.z = q16(x[n * 3 + 2] * d);
            v.w = 0;
            ((short4_t*)xs4)[n] = v;
        }
    }
}

// ---------------- FUSED: CSR gather (int16x4 loads, pure-int accumulation, x8 unroll)
//                  -> LDS -> matmul -> fp16 pre + fp64 stats ----------------
// Activations stored pre-quantized int16 -> inner loop is 8 VALU/edge (2 sext + 2 shift + 4 add),
// and integer addition makes the sum order-independent (deterministic for any CSR order).
template <int IN, int OUT, int INSTRIDE>
__global__ void gather_mm_kernel(const int* __restrict__ row_ptr, const int* __restrict__ deg,
                                 const int* __restrict__ sorted_row, const float* __restrict__ dis,
                                 const short* __restrict__ hs, const float* __restrict__ W,
                                 const float* __restrict__ b, _Float16* __restrict__ pre,
                                 double* __restrict__ part_s, double* __restrict__ part_q) {
    const int LPN = INSTRIDE / 4;  // lanes per node (feature-quads per node)
    const int NPW = 64 / LPN;      // nodes per wave
    const int NPB = 4 * NPW;       // nodes per block (256 threads)
    __shared__ float lds_agg[1024];  // NPB * INSTRIDE == 1024 floats always
    __shared__ float Ws[IN * OUT];
    __shared__ double s_s[256];
    __shared__ double s_q[256];
    int tid = threadIdx.x;
    for (int k = tid; k < IN * OUT; k += 256) Ws[k] = W[k];

    int wv = tid >> 6, lane = tid & 63;
    int jn = wv * NPW + lane / LPN;  // node index within block
    int p = lane % LPN;              // feature-quad index
    int n = blockIdx.x * NPB + jn;
    if (n < N_NODES) {
        int start = row_ptr[n];
        int d = deg[n];
        const int* sr = sorted_row + start;
        const int2* h2 = (const int2*)hs;  // one int2 = 4 packed int16
        int2 v = h2[(long long)n * LPN + p];
        int acc0 = (int)(short)v.x, acc1 = v.x >> 16;
        int acc2 = (int)(short)v.y, acc3 = v.y >> 16;
        int j = 0;
        for (; j + 8 <= d; j += 8) {
            int r0 = sr[j], r1 = sr[j + 1], r2 = sr[j + 2], r3 = sr[j + 3];
            int r4 = sr[j + 4], r5 = sr[j + 5], r6 = sr[j + 6], r7 = sr[j + 7];
            int2 a0 = h2[(long long)r0 * LPN + p];
            int2 a1 = h2[(long long)r1 * LPN + p];
            int2 a2 = h2[(long long)r2 * LPN + p];
            int2 a3 = h2[(long long)r3 * LPN + p];
            int2 a4 = h2[(long long)r4 * LPN + p];
            int2 a5 = h2[(long long)r5 * LPN + p];
            int2 a6 = h2[(long long)r6 * LPN + p];
            int2 a7 = h2[(long long)r7 * LPN + p];
            acc0 += (((int)(short)a0.x + (int)(short)a1.x) + ((int)(short)a2.x + (int)(short)a3.x)) +
                    (((int)(short)a4.x + (int)(short)a5.x) + ((int)(short)a6.x + (int)(short)a7.x));
            acc1 += (((a0.x >> 16) + (a1.x >> 16)) + ((a2.x >> 16) + (a3.x >> 16))) +
                    (((a4.x >> 16) + (a5.x >> 16)) + ((a6.x >> 16) + (a7.x >> 16)));
            acc2 += (((int)(short)a0.y + (int)(short)a1.y) + ((int)(short)a2.y + (int)(short)a3.y)) +
                    (((int)(short)a4.y + (int)(short)a5.y) + ((int)(short)a6.y + (int)(short)a7.y));
            acc3 += (((a0.y >> 16) + (a1.y >> 16)) + ((a2.y >> 16) + (a3.y >> 16))) +
                    (((a4.y >> 16) + (a5.y >> 16)) + ((a6.y >> 16) + (a7.y >> 16)));
        }
        for (; j < d; j++) {
            int2 a = h2[(long long)sr[j] * LPN + p];
            acc0 += (int)(short)a.x;
            acc1 += a.x >> 16;
            acc2 += (int)(short)a.y;
            acc3 += a.y >> 16;
        }
        float dn = dis[n] * QINV;
        float* dst = &lds_agg[(jn * LPN + p) * 4];
        dst[0] = dn * (float)acc0;
        dst[1] = dn * (float)acc1;
        dst[2] = dn * (float)acc2;
        dst[3] = dn * (float)acc3;
    }
    __syncthreads();

    // ---- matmul + stats phase (deterministic: fixed order over deterministic agg)
    const int NG = 256 / OUT;  // node groups
    int o = tid % OUT;
    int g = tid / OUT;
    float bo = b[o];
    double my_s = 0.0, my_q = 0.0;
    for (int j = g; j < NPB; j += NG) {
        int nn = blockIdx.x * NPB + j;
        if (nn < N_NODES) {
            float acc = bo;
#pragma unroll
            for (int k = 0; k < IN; k++) acc += lds_agg[j * INSTRIDE + k] * Ws[k * OUT + o];
            _Float16 q = (_Float16)acc;
            pre[(long long)nn * OUT + o] = q;
            float fq = (float)q;  // stats on quantized values
            my_s += (double)fq;
            my_q += (double)fq * (double)fq;
        }
    }
    s_s[tid] = my_s;
    s_q[tid] = my_q;
    __syncthreads();
    if (tid < OUT) {
        double ts = 0.0, tq = 0.0;
        for (int k = tid; k < 256; k += OUT) { ts += s_s[k]; tq += s_q[k]; }
        part_s[(long long)tid * NBMAX + blockIdx.x] = ts;
        part_q[(long long)tid * NBMAX + blockIdx.x] = tq;
    }
}

// ---------------- finalize BN stats: one block per feature, variable #partials ----------------
__global__ void bn_finalize_kernel(const double* __restrict__ part_s, const double* __restrict__ part_q,
                                   int nb, float* __restrict__ bn_mean, float* __restrict__ bn_rstd) {
    __shared__ double s_s[256];
    __shared__ double s_q[256];
    int o = blockIdx.x;
    int t = threadIdx.x;
    double ms = 0.0, mq = 0.0;
    for (int k = t; k < nb; k += 256) {
        ms += part_s[(long long)o * NBMAX + k];
        mq += part_q[(long long)o * NBMAX + k];
    }
    s_s[t] = ms;
    s_q[t] = mq;
    __syncthreads();
    for (int off = 128; off > 0; off >>= 1) {
        if (t < off) { s_s[t] += s_s[t + off]; s_q[t] += s_q[t + off]; }
        __syncthreads();
    }
    if (t == 0) {
        double mean = s_s[0] / (double)N_NODES;
        double var = s_q[0] / (double)N_NODES - mean * mean;
        bn_mean[o] = (float)mean;
        bn_rstd[o] = (float)(1.0 / sqrt(var + BN_EPS));
    }
}

// ---------------- BN apply + ReLU + dis pre-scale; fp16 in, INT16 fixed-point out ----------------
template <int F>
__global__ void bn_relu_kernel(const _Float16* __restrict__ pre, const float* __restrict__ bn_mean,
                               const float* __restrict__ bn_rstd, const float* __restrict__ g,
                               const float* __restrict__ be, const float* __restrict__ dis,
                               short* __restrict__ out) {
    const int GP = F / 4;  // quads per node
    int t = blockIdx.x * blockDim.x + threadIdx.x;
    const int total = N_NODES * GP;
    if (t >= total) return;
    int gi = t % GP;
    int f0 = gi * 4;
    half4_t v = ((const half4_t*)pre)[t];
    float d = dis[t / GP];
    short4_t o;
#pragma unroll
    for (int k = 0; k < 4; k++) {
        int f = f0 + k;
        float y = ((float)v[k] - bn_mean[f]) * bn_rstd[f] * g[f] + be[f];
        y = y > 0.f ? y : 0.f;
        o[k] = q16(y * d);
    }
    ((short4_t*)out)[t] = o;
}

// ---------------- mean pool with FUSED BN3+ReLU (reads fp16 PRE directly) ----------------
#define POOL_CHUNK 32
__global__ void pool_kernel(const _Float16* __restrict__ pre, const int* __restrict__ batch,
                            const float* __restrict__ bn_mean, const float* __restrict__ bn_rstd,
                            const float* __restrict__ g, const float* __restrict__ be,
                            float* __restrict__ pooled, float* __restrict__ cnt) {
    int wave = (blockIdx.x * blockDim.x + threadIdx.x) >> 6;
    int lane = threadIdx.x & 63;  // feature index
    int start = wave * POOL_CHUNK;
    if (start >= N_NODES) return;
    int end = start + POOL_CHUNK;
    if (end > N_NODES) end = N_NODES;
    float A = bn_rstd[lane] * g[lane];
    float B = be[lane] - bn_mean[lane] * A;
    int cur = batch[start];  // wave-uniform -> scalar load
    float acc = 0.f;
    float c = 0.f;
    int i = start;
    for (; i + 4 <= end; i += 4) {
        int b0 = batch[i], b1 = batch[i + 1], b2 = batch[i + 2], b3 = batch[i + 3];
        float v0 = fmaxf(0.f, fmaf((float)pre[(long long)i * 64 + lane], A, B));
        float v1 = fmaxf(0.f, fmaf((float)pre[(long long)(i + 1) * 64 + lane], A, B));
        float v2 = fmaxf(0.f, fmaf((float)pre[(long long)(i + 2) * 64 + lane], A, B));
        float v3 = fmaxf(0.f, fmaf((float)pre[(long long)(i + 3) * 64 + lane], A, B));
        if (b0 != cur) { atomicAdd(&pooled[cur * 64 + lane], acc); if (lane == 0) atomicAdd(&cnt[cur], c); acc = 0.f; c = 0.f; cur = b0; }
        acc += v0; c += 1.f;
        if (b1 != cur) { atomicAdd(&pooled[cur * 64 + lane], acc); if (lane == 0) atomicAdd(&cnt[cur], c); acc = 0.f; c = 0.f; cur = b1; }
        acc += v1; c += 1.f;
        if (b2 != cur) { atomicAdd(&pooled[cur * 64 + lane], acc); if (lane == 0) atomicAdd(&cnt[cur], c); acc = 0.f; c = 0.f; cur = b2; }
        acc += v2; c += 1.f;
        if (b3 != cur) { atomicAdd(&pooled[cur * 64 + lane], acc); if (lane == 0) atomicAdd(&cnt[cur], c); acc = 0.f; c = 0.f; cur = b3; }
        acc += v3; c += 1.f;
    }
    for (; i < end; i++) {
        int b = batch[i];
        if (b != cur) { atomicAdd(&pooled[cur * 64 + lane], acc); if (lane == 0) atomicAdd(&cnt[cur], c); acc = 0.f; c = 0.f; cur = b; }
        acc += fmaxf(0.f, fmaf((float)pre[(long long)i * 64 + lane], A, B)); c += 1.f;
    }
    atomicAdd(&pooled[cur * 64 + lane], acc);
    if (lane == 0) atomicAdd(&cnt[cur], c);
}

// ---------------- final linear ----------------
__global__ void final_kernel(const float* __restrict__ pooled, const float* __restrict__ cnt,
                             const float* __restrict__ fcW, const float* __restrict__ fcb,
                             float* __restrict__ out) {
    int t = blockIdx.x * blockDim.x + threadIdx.x;
    if (t >= B_GRAPHS * 10) return;
    int b = t / 10, j = t % 10;
    float inv = 1.0f / fmaxf(cnt[b], 1.0f);
    float acc = fcb[j];
#pragma unroll
    for (int f = 0; f < 64; f++) acc += pooled[b * 64 + f] * inv * fcW[f * 10 + j];
    out[t] = acc;
}

extern "C" void kernel_launch(void* const* d_in, const int* in_sizes, int n_in,
                              void* d_out, int out_size, void* d_ws, size_t ws_size,
                              hipStream_t stream) {
    const float* x  = (const float*)d_in[0];
    const int* ei   = (const int*)d_in[1];
    const int* batch= (const int*)d_in[2];
    const float* W1 = (const float*)d_in[3];  const float* b1 = (const float*)d_in[4];
    const float* g1 = (const float*)d_in[5];  const float* be1= (const float*)d_in[6];
    const float* W2 = (const float*)d_in[7];  const float* b2 = (const float*)d_in[8];
    const float* g2 = (const float*)d_in[9];  const float* be2= (const float*)d_in[10];
    const float* W3 = (const float*)d_in[11]; const float* b3 = (const float*)d_in[12];
    const float* g3 = (const float*)d_in[13]; const float* be3= (const float*)d_in[14];
    const float* fcW= (const float*)d_in[15]; const float* fcb= (const float*)d_in[16];
    float* out = (float*)d_out;

    const int* row = ei;
    const int* col = ei + N_EDGES;

    // workspace layout — zero region first (one memset): bucket_cnt, pooled, cnt
    char* wp = (char*)d_ws;
    int*   bucket_cnt = (int*)wp;                wp += NBUCK * 4;
    float* pooled     = (float*)wp;              wp += 64 * 64 * 4;
    float* cnt        = (float*)wp;              wp += 64 * 4;
    const size_t ZERO_BYTES = NBUCK * 4 + 64 * 64 * 4 + 64 * 4;
    float* dis        = (float*)wp;              wp += N_NODES * 4;
    int*   deg_i      = (int*)wp;                wp += N_NODES * 4;
    int*   row_ptr    = (int*)wp;                wp += N_NODES * 4;
    int*   bucket_base= (int*)wp;                wp += NBUCK * 4;
    int*   bucket_cur = (int*)wp;                wp += NBUCK * 4;
    int*   sorted_row = (int*)wp;                wp += (size_t)N_EDGES * 4;
    unsigned* part_edges = (unsigned*)wp;        wp += (size_t)N_EDGES * 4;
    double* part_s    = (double*)wp;             wp += (size_t)NBMAX * 64 * 8;
    double* part_q    = (double*)wp;             wp += (size_t)NBMAX * 64 * 8;
    float* bn_mean    = (float*)wp;              wp += 64 * 4;
    float* bn_rstd    = (float*)wp;              wp += 64 * 4;
    short* xs4q       = (short*)wp;              wp += (size_t)N_NODES * 4 * 2;
    _Float16* PRE     = (_Float16*)wp;           wp += (size_t)N_NODES * 64 * 2;  // matmul out (fp16)
    short* Hq         = (short*)wp;              wp += (size_t)N_NODES * 32 * 2;  // h1/h2 (int16 fxp, pre-scaled)

    const int BS = 256;

    // ---- one memset for all zero-init state
    hipMemsetAsync(bucket_cnt, 0, ZERO_BYTES, stream);

    // ---- CSR build: bucketed two-phase (order-nondeterministic — harmless); emits xs4q
    part_hist_kernel<<<NB_PART, 256, 0, stream>>>(col, bucket_cnt);
    part_scan_kernel<<<1, NBUCK, 0, stream>>>(bucket_cnt, bucket_base, bucket_cur);
    part_scatter_kernel<<<NB_PART, 256, 0, stream>>>(row, col, bucket_cur, part_edges);
    csr_build_kernel<<<NBUCK, 256, 0, stream>>>(bucket_base, part_edges, row_ptr, deg_i, dis, sorted_row, x, xs4q);

    // ---- layer 1: fused gather(F=4)+matmul 3->16  (NPB=256 -> 391 blocks)
    const int NB1 = cdiv(N_NODES, 256);
    gather_mm_kernel<3, 16, 4><<<NB1, 256, 0, stream>>>(
        row_ptr, deg_i, sorted_row, dis, xs4q, W1, b1, PRE, part_s, part_q);
    bn_finalize_kernel<<<16, 256, 0, stream>>>(part_s, part_q, NB1, bn_mean, bn_rstd);
    bn_relu_kernel<16><<<cdiv((long long)N_NODES * 4, BS), BS, 0, stream>>>(
        PRE, bn_mean, bn_rstd, g1, be1, dis, Hq);  // Hq = h1 * dis (int16 fxp)

    // ---- layer 2: fused gather(F=16)+matmul 16->32  (NPB=64 -> 1563 blocks)
    const int NB2 = cdiv(N_NODES, 64);
    gather_mm_kernel<16, 32, 16><<<NB2, 256, 0, stream>>>(
        row_ptr, deg_i, sorted_row, dis, Hq, W2, b2, PRE, part_s, part_q);
    bn_finalize_kernel<<<32, 256, 0, stream>>>(part_s, part_q, NB2, bn_mean, bn_rstd);
    bn_relu_kernel<32><<<cdiv((long long)N_NODES * 8, BS), BS, 0, stream>>>(
        PRE, bn_mean, bn_rstd, g2, be2, dis, Hq);  // Hq = h2 * dis (int16 fxp)

    // ---- layer 3: fused gather(F=32)+matmul 32->64  (NPB=32 -> 3125 blocks)
    const int NB3 = cdiv(N_NODES, 32);
    gather_mm_kernel<32, 64, 32><<<NB3, 256, 0, stream>>>(
        row_ptr, deg_i, sorted_row, dis, Hq, W3, b3, PRE, part_s, part_q);
    bn_finalize_kernel<<<64, 256, 0, stream>>>(part_s, part_q, NB3, bn_mean, bn_rstd);

    // ---- pool (fused BN3+ReLU) + fc
    pool_kernel<<<cdiv((long long)cdiv(N_NODES, POOL_CHUNK) * 64, BS), BS, 0, stream>>>(
        PRE, batch, bn_mean, bn_rstd, g3, be3, pooled, cnt);
    final_kernel<<<1, B_GRAPHS * 10, 0, stream>>>(pooled, cnt, fcW, fcb, out);
}